// Round 9
// baseline (74.418 us; speedup 1.0000x reference)
//
#include <hip/hip_runtime.h>
#include <math.h>

#define BB 64
#define TT 2048
#define DD 512
#define UU 10
#define S_CHUNKS 16
#define CHUNK_T (TT / S_CHUNKS)   // 128 t per block, 32 per wave
#define NB (CHUNK_T / 8)          // 16 batches of 2 t per wave

__device__ __forceinline__ float fast_tanh(float x) {
    // tanh(x) = 1 - 2/(1+e^{2x}); robust at +-inf
    return 1.0f - 2.0f / (1.0f + __expf(2.0f * x));
}

// DPP row_shr:K accumulate (VALU pipe): lane i reads lane i-K within its
// 16-lane row; out-of-row reads return 0 (bound_ctrl). Chaining K=1,2,4,8
// leaves the full row sum in lane 15 of each row. (Proven R5: absmax 1e-4.)
template<int K>
__device__ __forceinline__ float dpp_shr(float x) {
    int xi = __builtin_bit_cast(int, x);
    int r  = __builtin_amdgcn_update_dpp(0, xi, 0x110 | K, 0xF, 0xF, true);
    return __builtin_bit_cast(float, r);
}

__device__ __forceinline__ float read_lane_f(float v, int lane) {
    return __builtin_bit_cast(float,
        __builtin_amdgcn_readlane(__builtin_bit_cast(int, v), lane));
}

// Scores are bounded: |s| <= |b_s| + sum|W_s| (tanh in [-1,1]) ~ 4, so exp(s)
// never overflows and softmax needs NO max subtraction: p = exp(s), w = p/sum(p).
//
// 2-t batches: acc[2][10]+e[2][8] keeps live VGPRs ~155-165 (vs ~185 at 4-t),
// aiming under the 168-VGPR threshold for 3 waves/SIMD. NO launch_bounds pin
// (R4: pinning the allocator forces wv[] to scratch — 84 VGPR + 350MB spill).
// Fold network is a strict subset of the R5-proven one (permlane abandoned:
// R6-R8 showed both asm and builtin forms disagree with documented semantics).
__global__ __launch_bounds__(256) void attn_pass1(
    const float* __restrict__ Eo, const float* __restrict__ H,
    const float* __restrict__ W_eo, const float* __restrict__ b_eo,
    const float* __restrict__ W_h, const float* __restrict__ b_h,
    const float* __restrict__ W_s, const float* __restrict__ b_s,
    float* __restrict__ pexp, float* __restrict__ pc)
{
    const int b     = blockIdx.y;
    const int chunk = blockIdx.x;
    const int tid   = threadIdx.x;
    const int wave  = tid >> 6;
    const int lane  = tid & 63;

    // ---- hb[u] = (H[b]*W_h)[u] + b_h[u] + b_eo[u]  (once per wave)
    float hacc[UU];
    #pragma unroll
    for (int u = 0; u < UU; ++u) hacc[u] = 0.f;
    const float* Hb = H + (size_t)b * DD;
    #pragma unroll
    for (int k = 0; k < DD / 64; ++k) {
        float hv = Hb[k * 64 + lane];
        const float* wr = W_h + (size_t)(k * 64 + lane) * UU;
        #pragma unroll
        for (int u = 0; u < UU; ++u) hacc[u] += hv * wr[u];
    }
    #pragma unroll
    for (int off = 1; off < 64; off <<= 1) {
        #pragma unroll
        for (int u = 0; u < UU; ++u) hacc[u] += __shfl_xor(hacc[u], off, 64);
    }
    float hb[UU];
    #pragma unroll
    for (int u = 0; u < UU; ++u) hb[u] = hacc[u] + b_h[u] + b_eo[u];

    float wsv[UU];
    #pragma unroll
    for (int u = 0; u < UU; ++u) wsv[u] = W_s[u];   // uniform -> scalar loads
    const float bs = b_s[0];

    // ---- per-lane W_eo slice (80 VGPRs, loaded once, reused for all t)
    float wv[8][UU];
    #pragma unroll
    for (int k = 0; k < 2; ++k) {
        #pragma unroll
        for (int j = 0; j < 4; ++j) {
            const float* wr = W_eo + (size_t)(k * 256 + 4 * lane + j) * UU;
            #pragma unroll
            for (int u = 0; u < UU; ++u) wv[k * 4 + j][u] = wr[u];
        }
    }

    float l = 0.f;
    float c[8];
    #pragma unroll
    for (int j = 0; j < 8; ++j) c[j] = 0.f;

    const int  t0w  = chunk * CHUNK_T + wave * (CHUNK_T / 4);
    const bool lo32 = (lane & 32) == 0;
    const float* rowbase = Eo + (size_t)b * TT * DD + 4 * lane;

    for (int i = 0; i < NB; ++i) {      // 16 batches of 2 t
        const int tb = t0w + i * 2;

        // load e for 2 t's (4 independent float4 loads)
        float e[2][8];
        #pragma unroll
        for (int tt = 0; tt < 2; ++tt) {
            const float* row = rowbase + (size_t)(tb + tt) * DD;
            float4 e0 = *(const float4*)(row);
            float4 e1 = *(const float4*)(row + 256);
            e[tt][0] = e0.x; e[tt][1] = e0.y; e[tt][2] = e0.z; e[tt][3] = e0.w;
            e[tt][4] = e1.x; e[tt][5] = e1.y; e[tt][6] = e1.z; e[tt][7] = e1.w;
        }

        // per-lane partial projections for 2 t's
        float acc[2][UU];
        #pragma unroll
        for (int tt = 0; tt < 2; ++tt) {
            #pragma unroll
            for (int u = 0; u < UU; ++u) acc[tt][u] = 0.f;
            #pragma unroll
            for (int j = 0; j < 8; ++j) {
                #pragma unroll
                for (int u = 0; u < UU; ++u) acc[tt][u] += e[tt][j] * wv[j][u];
            }
        }

        // fold-reduce (R5-proven subnetwork):
        //   select + xor32 : y = t0 folded in lanes<32, t1 in lanes>=32
        //   xor16          : rows 0,1 = t0 halves-folded; rows 2,3 = t1
        //   4x DPP row_shr : full sum in lane 15 (t0) and lane 47 (t1)
        float s = bs;
        #pragma unroll
        for (int u = 0; u < UU; ++u) {
            float y = lo32 ? acc[0][u] : acc[1][u];
            float o = lo32 ? acc[1][u] : acc[0][u];
            y += __shfl_xor(o, 32, 64);
            y += __shfl_xor(y, 16, 64);
            y += dpp_shr<1>(y);
            y += dpp_shr<2>(y);
            y += dpp_shr<4>(y);
            y += dpp_shr<8>(y);
            // true sums in lanes 15,31 (t0) and 47,63 (t1); others bounded
            s += wsv[u] * fast_tanh(y + hb[u]);
        }
        float p = __expf(s);

        if (lane == 15) pexp[(size_t)b * TT + tb]     = p;
        if (lane == 47) pexp[(size_t)b * TT + tb + 1] = p;

        // broadcast the 2 valid p's via readlane (SGPR, no DS traffic)
        float p0 = read_lane_f(p, 15);
        float p1 = read_lane_f(p, 47);
        l += p0 + p1;
        #pragma unroll
        for (int j = 0; j < 8; ++j)
            c[j] += p0 * e[0][j] + p1 * e[1][j];
    }

    // ---- combine the block's 4 waves in LDS (l recomputed from pexp in epilogue)
    __shared__ float sc[4][DD];
    #pragma unroll
    for (int k = 0; k < 2; ++k) {
        #pragma unroll
        for (int j = 0; j < 4; ++j)
            sc[wave][k * 256 + 4 * lane + j] = c[k * 4 + j];
    }
    __syncthreads();

    const int pidx = b * S_CHUNKS + chunk;
    for (int d = tid; d < DD; d += 256) {
        pc[(size_t)pidx * DD + d] = (sc[0][d] + sc[1][d]) + (sc[2][d] + sc[3][d]);
    }
}

// Fused epilogue, 4 blocks per batch b: each block computes l redundantly
// (8KB read), then handles a quarter of the weights and a quarter of context.
__global__ __launch_bounds__(256) void attn_epilogue(
    const float* __restrict__ pexp, const float* __restrict__ pc,
    float* __restrict__ ctx_out, float* __restrict__ wout)
{
    const int b    = blockIdx.x >> 2;
    const int part = blockIdx.x & 3;
    const int tid  = threadIdx.x;
    const int wave = tid >> 6;

    // l = sum over 2048 pexp values (all 4 blocks of b compute identically)
    float s = 0.f;
    #pragma unroll
    for (int k = 0; k < TT / 256; ++k) s += pexp[(size_t)b * TT + k * 256 + tid];
    #pragma unroll
    for (int off = 1; off < 64; off <<= 1) s += __shfl_xor(s, off, 64);

    __shared__ float sl[4];
    if ((tid & 63) == 0) sl[wave] = s;
    __syncthreads();
    const float l = (sl[0] + sl[1]) + (sl[2] + sl[3]);
    const float inv = 1.0f / l;

    // context quarter: 128 d's
    const int d = part * (DD / 4) + tid;
    if (tid < DD / 4) {
        float v = 0.f;
        #pragma unroll
        for (int sss = 0; sss < S_CHUNKS; ++sss)
            v += pc[((size_t)(b * S_CHUNKS + sss)) * DD + d];
        ctx_out[(size_t)b * DD + d] = v * inv;
    }
    // weight quarter: 512 t's
    #pragma unroll
    for (int k = 0; k < 2; ++k) {
        const int t = part * (TT / 4) + k * 256 + tid;
        wout[(size_t)b * TT + t] = pexp[(size_t)b * TT + t] * inv;
    }
}

extern "C" void kernel_launch(void* const* d_in, const int* in_sizes, int n_in,
                              void* d_out, int out_size, void* d_ws, size_t ws_size,
                              hipStream_t stream) {
    const float* Eo   = (const float*)d_in[0];
    const float* H    = (const float*)d_in[1];
    const float* W_eo = (const float*)d_in[2];
    const float* b_eo = (const float*)d_in[3];
    const float* W_h  = (const float*)d_in[4];
    const float* b_h  = (const float*)d_in[5];
    const float* W_s  = (const float*)d_in[6];
    const float* b_s  = (const float*)d_in[7];

    // ws layout (floats): pexp[B*T] | pc[B*S*D]
    float* pexp = (float*)d_ws;
    float* pc   = pexp + (size_t)BB * TT;

    float* out_ctx = (float*)d_out;                 // [B, D]
    float* out_w   = out_ctx + (size_t)BB * DD;     // [B, T, 1]

    dim3 gridA(S_CHUNKS, BB);
    attn_pass1<<<gridA, 256, 0, stream>>>(Eo, H, W_eo, b_eo, W_h, b_h, W_s, b_s,
                                          pexp, pc);
    attn_epilogue<<<BB * 4, 256, 0, stream>>>(pexp, pc, out_ctx, out_w);
}

// Round 10
// 72.691 us; speedup vs baseline: 1.0237x; 1.0237x over previous
//
#include <hip/hip_runtime.h>
#include <math.h>

#define BB 64
#define TT 2048
#define DD 512
#define UU 10
#define S_CHUNKS 16
#define CHUNK_T (TT / S_CHUNKS)   // 128 t per block, 32 per wave, 8 batches of 4
#define NB (CHUNK_T / 16)         // 8 load-batches of 4 t per wave

__device__ __forceinline__ float fast_tanh(float x) {
    // tanh(x) = 1 - 2/(1+e^{2x}); robust at +-inf
    return 1.0f - 2.0f / (1.0f + __expf(2.0f * x));
}

// DPP row_shr:K accumulate (VALU pipe): lane i reads lane i-K within its
// 16-lane row; out-of-row reads return 0 (bound_ctrl). Chaining K=1,2,4,8
// leaves the full row sum in lane 15 of each row. (Proven R5/R9.)
template<int K>
__device__ __forceinline__ float dpp_shr(float x) {
    int xi = __builtin_bit_cast(int, x);
    int r  = __builtin_amdgcn_update_dpp(0, xi, 0x110 | K, 0xF, 0xF, true);
    return __builtin_bit_cast(float, r);
}

__device__ __forceinline__ float read_lane_f(float v, int lane) {
    return __builtin_bit_cast(float,
        __builtin_amdgcn_readlane(__builtin_bit_cast(int, v), lane));
}

__device__ __forceinline__ float first_lane_f(float v) {
    return __builtin_bit_cast(float,
        __builtin_amdgcn_readfirstlane(__builtin_bit_cast(int, v)));
}

// Scores are bounded: |s| <= |b_s| + sum|W_s| (tanh in [-1,1]) ~ 4, so exp(s)
// never overflows and softmax needs NO max subtraction: p = exp(s), w = p/sum(p).
//
// Structure: R5's 4-t e-loads (8 float4 in flight = proven MLP) but proj+fold
// as 2x2-t (R9's proven network), ctx-accumulating after each half so e[0..1]
// dies early. acc 40->20 VGPRs; hb[] forced to SGPR via readfirstlane
// (uniform after butterfly). Target <=168 VGPR -> 3 waves/SIMD, NO pin
// (R4: pinning forces wv[] to scratch).
__global__ __launch_bounds__(256) void attn_pass1(
    const float* __restrict__ Eo, const float* __restrict__ H,
    const float* __restrict__ W_eo, const float* __restrict__ b_eo,
    const float* __restrict__ W_h, const float* __restrict__ b_h,
    const float* __restrict__ W_s, const float* __restrict__ b_s,
    float* __restrict__ pexp, float* __restrict__ pc)
{
    const int b     = blockIdx.y;
    const int chunk = blockIdx.x;
    const int tid   = threadIdx.x;
    const int wave  = tid >> 6;
    const int lane  = tid & 63;

    // ---- hb[u] = (H[b]*W_h)[u] + b_h[u] + b_eo[u]  (once per wave)
    float hacc[UU];
    #pragma unroll
    for (int u = 0; u < UU; ++u) hacc[u] = 0.f;
    const float* Hb = H + (size_t)b * DD;
    #pragma unroll
    for (int k = 0; k < DD / 64; ++k) {
        float hv = Hb[k * 64 + lane];
        const float* wr = W_h + (size_t)(k * 64 + lane) * UU;
        #pragma unroll
        for (int u = 0; u < UU; ++u) hacc[u] += hv * wr[u];
    }
    #pragma unroll
    for (int off = 1; off < 64; off <<= 1) {
        #pragma unroll
        for (int u = 0; u < UU; ++u) hacc[u] += __shfl_xor(hacc[u], off, 64);
    }
    // uniform after full butterfly -> force into SGPRs (frees 10 VGPRs)
    float hb[UU];
    #pragma unroll
    for (int u = 0; u < UU; ++u) hb[u] = first_lane_f(hacc[u]) + b_h[u] + b_eo[u];

    float wsv[UU];
    #pragma unroll
    for (int u = 0; u < UU; ++u) wsv[u] = W_s[u];   // uniform -> scalar loads
    const float bs = b_s[0];

    // ---- per-lane W_eo slice (80 VGPRs, loaded once, reused for all t)
    float wv[8][UU];
    #pragma unroll
    for (int k = 0; k < 2; ++k) {
        #pragma unroll
        for (int j = 0; j < 4; ++j) {
            const float* wr = W_eo + (size_t)(k * 256 + 4 * lane + j) * UU;
            #pragma unroll
            for (int u = 0; u < UU; ++u) wv[k * 4 + j][u] = wr[u];
        }
    }

    float l = 0.f;
    float c[8];
    #pragma unroll
    for (int j = 0; j < 8; ++j) c[j] = 0.f;

    const int  t0w  = chunk * CHUNK_T + wave * (CHUNK_T / 4);
    const bool lo32 = (lane & 32) == 0;
    const float* rowbase = Eo + (size_t)b * TT * DD + 4 * lane;

    for (int i = 0; i < NB; ++i) {      // 8 batches: load 4 t, fold 2x2
        const int tb = t0w + i * 4;

        // load e for 4 t's up front (8 independent float4 loads in flight)
        float e[4][8];
        #pragma unroll
        for (int tt = 0; tt < 4; ++tt) {
            const float* row = rowbase + (size_t)(tb + tt) * DD;
            float4 e0 = *(const float4*)(row);
            float4 e1 = *(const float4*)(row + 256);
            e[tt][0] = e0.x; e[tt][1] = e0.y; e[tt][2] = e0.z; e[tt][3] = e0.w;
            e[tt][4] = e1.x; e[tt][5] = e1.y; e[tt][6] = e1.z; e[tt][7] = e1.w;
        }

        // two half-batches of 2 t each (R9-proven fold network)
        #pragma unroll
        for (int h = 0; h < 2; ++h) {
            const int ta = 2 * h;        // t indices ta, ta+1 within batch

            float acc[2][UU];
            #pragma unroll
            for (int tt = 0; tt < 2; ++tt) {
                #pragma unroll
                for (int u = 0; u < UU; ++u) acc[tt][u] = 0.f;
                #pragma unroll
                for (int j = 0; j < 8; ++j) {
                    #pragma unroll
                    for (int u = 0; u < UU; ++u)
                        acc[tt][u] += e[ta + tt][j] * wv[j][u];
                }
            }

            // fold-reduce (R9-proven): select+xor32 -> t_a in lanes<32,
            // t_{a+1} in lanes>=32; xor16; 4x DPP row_shr -> sums in
            // lanes 15,31 (t_a) and 47,63 (t_{a+1}).
            float s = bs;
            #pragma unroll
            for (int u = 0; u < UU; ++u) {
                float y = lo32 ? acc[0][u] : acc[1][u];
                float o = lo32 ? acc[1][u] : acc[0][u];
                y += __shfl_xor(o, 32, 64);
                y += __shfl_xor(y, 16, 64);
                y += dpp_shr<1>(y);
                y += dpp_shr<2>(y);
                y += dpp_shr<4>(y);
                y += dpp_shr<8>(y);
                s += wsv[u] * fast_tanh(y + hb[u]);
            }
            float p = __expf(s);

            if (lane == 15) pexp[(size_t)b * TT + tb + ta]     = p;
            if (lane == 47) pexp[(size_t)b * TT + tb + ta + 1] = p;

            float p0 = read_lane_f(p, 15);
            float p1 = read_lane_f(p, 47);
            l += p0 + p1;
            // ctx accumulate NOW so e[ta..ta+1] dies before next half
            #pragma unroll
            for (int j = 0; j < 8; ++j)
                c[j] += p0 * e[ta][j] + p1 * e[ta + 1][j];
        }
    }

    // ---- combine the block's 4 waves in LDS (l recomputed from pexp in epilogue)
    __shared__ float sc[4][DD];
    #pragma unroll
    for (int k = 0; k < 2; ++k) {
        #pragma unroll
        for (int j = 0; j < 4; ++j)
            sc[wave][k * 256 + 4 * lane + j] = c[k * 4 + j];
    }
    __syncthreads();

    const int pidx = b * S_CHUNKS + chunk;
    for (int d = tid; d < DD; d += 256) {
        pc[(size_t)pidx * DD + d] = (sc[0][d] + sc[1][d]) + (sc[2][d] + sc[3][d]);
    }
}

// Fused epilogue, 4 blocks per batch b (R9-proven): each block computes l
// redundantly (8KB read), then a quarter of weights and context.
__global__ __launch_bounds__(256) void attn_epilogue(
    const float* __restrict__ pexp, const float* __restrict__ pc,
    float* __restrict__ ctx_out, float* __restrict__ wout)
{
    const int b    = blockIdx.x >> 2;
    const int part = blockIdx.x & 3;
    const int tid  = threadIdx.x;
    const int wave = tid >> 6;

    float s = 0.f;
    #pragma unroll
    for (int k = 0; k < TT / 256; ++k) s += pexp[(size_t)b * TT + k * 256 + tid];
    #pragma unroll
    for (int off = 1; off < 64; off <<= 1) s += __shfl_xor(s, off, 64);

    __shared__ float sl[4];
    if ((tid & 63) == 0) sl[wave] = s;
    __syncthreads();
    const float l = (sl[0] + sl[1]) + (sl[2] + sl[3]);
    const float inv = 1.0f / l;

    const int d = part * (DD / 4) + tid;
    if (tid < DD / 4) {
        float v = 0.f;
        #pragma unroll
        for (int sss = 0; sss < S_CHUNKS; ++sss)
            v += pc[((size_t)(b * S_CHUNKS + sss)) * DD + d];
        ctx_out[(size_t)b * DD + d] = v * inv;
    }
    #pragma unroll
    for (int k = 0; k < 2; ++k) {
        const int t = part * (TT / 4) + k * 256 + tid;
        wout[(size_t)b * TT + t] = pexp[(size_t)b * TT + t] * inv;
    }
}

extern "C" void kernel_launch(void* const* d_in, const int* in_sizes, int n_in,
                              void* d_out, int out_size, void* d_ws, size_t ws_size,
                              hipStream_t stream) {
    const float* Eo   = (const float*)d_in[0];
    const float* H    = (const float*)d_in[1];
    const float* W_eo = (const float*)d_in[2];
    const float* b_eo = (const float*)d_in[3];
    const float* W_h  = (const float*)d_in[4];
    const float* b_h  = (const float*)d_in[5];
    const float* W_s  = (const float*)d_in[6];
    const float* b_s  = (const float*)d_in[7];

    // ws layout (floats): pexp[B*T] | pc[B*S*D]
    float* pexp = (float*)d_ws;
    float* pc   = pexp + (size_t)BB * TT;

    float* out_ctx = (float*)d_out;                 // [B, D]
    float* out_w   = out_ctx + (size_t)BB * DD;     // [B, T, 1]

    dim3 gridA(S_CHUNKS, BB);
    attn_pass1<<<gridA, 256, 0, stream>>>(Eo, H, W_eo, b_eo, W_h, b_h, W_s, b_s,
                                          pexp, pc);
    attn_epilogue<<<BB * 4, 256, 0, stream>>>(pexp, pc, out_ctx, out_w);
}

// Round 12
// 65.324 us; speedup vs baseline: 1.1392x; 1.1128x over previous
//
#include <hip/hip_runtime.h>
#include <math.h>

#define BB 64
#define TT 2048
#define DD 512
#define UU 10
#define S_CHUNKS 16
#define CHUNK_T (TT / S_CHUNKS)   // 128 t per block, 32 per wave, 8 batches of 4
#define NB (CHUNK_T / 16)         // 8 batches per wave

__device__ __forceinline__ float fast_tanh(float x) {
    // tanh(x) = 1 - 2/(1+e^{2x}); robust at +-inf
    return 1.0f - 2.0f / (1.0f + __expf(2.0f * x));
}

// DPP row_shr:K accumulate (VALU pipe). Proven R5/R9/R10.
template<int K>
__device__ __forceinline__ float dpp_shr(float x) {
    int xi = __builtin_bit_cast(int, x);
    int r  = __builtin_amdgcn_update_dpp(0, xi, 0x110 | K, 0xF, 0xF, true);
    return __builtin_bit_cast(float, r);
}

__device__ __forceinline__ float read_lane_f(float v, int lane) {
    return __builtin_bit_cast(float,
        __builtin_amdgcn_readlane(__builtin_bit_cast(int, v), lane));
}

// Async global->LDS DMA, 16B per lane: LDS dest = wave-uniform base + lane*16,
// global src = per-lane address. Counts in vmcnt.
typedef __attribute__((address_space(1))) const void gvoid;
typedef __attribute__((address_space(3))) void lvoid;
__device__ __forceinline__ void dma16(const float* g, float* l) {
    __builtin_amdgcn_global_load_lds((gvoid*)g, (lvoid*)l, 16, 0, 0);
}

// Scores are bounded: |s| <= |b_s| + sum|W_s| (tanh in [-1,1]) ~ 4, so exp(s)
// never overflows and softmax needs NO max subtraction: p = exp(s), w = p/sum(p).
//
// R12 = R11 with the vmcnt off-by-one fixed. Per batch there is exactly ONE
// masked pexp store (one vmem op). At iter i's wait the in-order-issued
// outstanding ops are [8 DMAs of tile i, 1 store of iter i-1]: vmcnt(1)
// completes everything except the single youngest op (the store), so all
// DMAs are guaranteed landed. R11's vmcnt(2) left the youngest DMA
// (tt=3 second half) unguaranteed -> absmax 1.5e-2.
__global__ __launch_bounds__(256) void attn_pass1(
    const float* __restrict__ Eo, const float* __restrict__ H,
    const float* __restrict__ W_eo, const float* __restrict__ b_eo,
    const float* __restrict__ W_h, const float* __restrict__ b_h,
    const float* __restrict__ W_s, const float* __restrict__ b_s,
    float* __restrict__ pexp, float* __restrict__ pc)
{
    const int b     = blockIdx.y;
    const int chunk = blockIdx.x;
    const int tid   = threadIdx.x;
    const int wave  = tid >> 6;
    const int lane  = tid & 63;

    __shared__ __align__(16) float buf[4][2][4][DD];  // 64 KB: per-wave dbuf tiles
    __shared__ float sc[4][DD];                        // 8 KB: wave combine

    // ---- hb[u] = (H[b]*W_h)[u] + b_h[u] + b_eo[u]  (once per wave)
    float hacc[UU];
    #pragma unroll
    for (int u = 0; u < UU; ++u) hacc[u] = 0.f;
    const float* Hb = H + (size_t)b * DD;
    #pragma unroll
    for (int k = 0; k < DD / 64; ++k) {
        float hv = Hb[k * 64 + lane];
        const float* wr = W_h + (size_t)(k * 64 + lane) * UU;
        #pragma unroll
        for (int u = 0; u < UU; ++u) hacc[u] += hv * wr[u];
    }
    #pragma unroll
    for (int off = 1; off < 64; off <<= 1) {
        #pragma unroll
        for (int u = 0; u < UU; ++u) hacc[u] += __shfl_xor(hacc[u], off, 64);
    }
    float hb[UU];
    #pragma unroll
    for (int u = 0; u < UU; ++u) hb[u] = hacc[u] + b_h[u] + b_eo[u];

    float wsv[UU];
    #pragma unroll
    for (int u = 0; u < UU; ++u) wsv[u] = W_s[u];   // uniform -> scalar loads
    const float bs = b_s[0];

    // ---- per-lane W_eo slice (80 VGPRs, loaded once, reused for all t)
    float wv[8][UU];
    #pragma unroll
    for (int k = 0; k < 2; ++k) {
        #pragma unroll
        for (int j = 0; j < 4; ++j) {
            const float* wr = W_eo + (size_t)(k * 256 + 4 * lane + j) * UU;
            #pragma unroll
            for (int u = 0; u < UU; ++u) wv[k * 4 + j][u] = wr[u];
        }
    }

    float l = 0.f;
    float c[8];
    #pragma unroll
    for (int j = 0; j < 8; ++j) c[j] = 0.f;

    const int  t0w  = chunk * CHUNK_T + wave * (CHUNK_T / 4);
    const bool lo32 = (lane & 32) == 0;
    const bool lo16 = (lane & 16) == 0;
    const float* rowb = Eo + (size_t)b * TT * DD + 4 * lane;   // per-lane src

    // ---- prologue: DMA tile 0
    #pragma unroll
    for (int tt = 0; tt < 4; ++tt) {
        const float* g = rowb + (size_t)(t0w + tt) * DD;
        dma16(g,       &buf[wave][0][tt][0]);
        dma16(g + 256, &buf[wave][0][tt][256]);
    }

    auto do_batch = [&](int i) {
        const int cur = i & 1, nxt = cur ^ 1;
        // issue next tile's DMAs first (hidden under this batch's compute)
        if (i + 1 < NB) {
            #pragma unroll
            for (int tt = 0; tt < 4; ++tt) {
                const float* g = rowb + (size_t)(t0w + (i + 1) * 4 + tt) * DD;
                dma16(g,       &buf[wave][nxt][tt][0]);
                dma16(g + 256, &buf[wave][nxt][tt][256]);
            }
        }
        __builtin_amdgcn_sched_barrier(0);   // pin issues before compute

        const int tb = t0w + i * 4;
        float e[4][8];
        #pragma unroll
        for (int tt = 0; tt < 4; ++tt) {
            float4 e0 = *(const float4*)&buf[wave][cur][tt][4 * lane];
            float4 e1 = *(const float4*)&buf[wave][cur][tt][256 + 4 * lane];
            e[tt][0] = e0.x; e[tt][1] = e0.y; e[tt][2] = e0.z; e[tt][3] = e0.w;
            e[tt][4] = e1.x; e[tt][5] = e1.y; e[tt][6] = e1.z; e[tt][7] = e1.w;
        }

        float acc[4][UU];
        #pragma unroll
        for (int tt = 0; tt < 4; ++tt) {
            #pragma unroll
            for (int u = 0; u < UU; ++u) acc[tt][u] = 0.f;
            #pragma unroll
            for (int j = 0; j < 8; ++j) {
                #pragma unroll
                for (int u = 0; u < UU; ++u) acc[tt][u] += e[tt][j] * wv[j][u];
            }
        }

        // fold-reduce (R5-proven): select+xor32 x2, select+xor16, 4x DPP
        float s = bs;
        #pragma unroll
        for (int u = 0; u < UU; ++u) {
            float y0 = lo32 ? acc[0][u] : acc[2][u];
            float o0 = lo32 ? acc[2][u] : acc[0][u];
            y0 += __shfl_xor(o0, 32, 64);
            float y1 = lo32 ? acc[1][u] : acc[3][u];
            float o1 = lo32 ? acc[3][u] : acc[1][u];
            y1 += __shfl_xor(o1, 32, 64);
            float z  = lo16 ? y0 : y1;
            float oz = lo16 ? y1 : y0;
            z += __shfl_xor(oz, 16, 64);
            z += dpp_shr<1>(z);
            z += dpp_shr<2>(z);
            z += dpp_shr<4>(z);
            z += dpp_shr<8>(z);
            s += wsv[u] * fast_tanh(z + hb[u]);
        }
        float p = __expf(s);

        if ((lane & 15) == 15) pexp[(size_t)b * TT + tb + (lane >> 4)] = p;

        float p0 = read_lane_f(p, 15);
        float p1 = read_lane_f(p, 31);
        float p2 = read_lane_f(p, 47);
        float p3 = read_lane_f(p, 63);
        l += (p0 + p1) + (p2 + p3);
        #pragma unroll
        for (int j = 0; j < 8; ++j)
            c[j] += p0 * e[0][j] + p1 * e[1][j] + p2 * e[2][j] + p3 * e[3][j];
    };

    // peeled first iteration: wait for ALL (only tile 0 outstanding)
    asm volatile("s_waitcnt vmcnt(0)" ::: "memory");
    __builtin_amdgcn_sched_barrier(0);
    do_batch(0);
    for (int i = 1; i < NB; ++i) {
        // outstanding (issue order): [8 DMAs tile i, 1 store iter i-1].
        // vmcnt(1): all but the youngest (the store) complete => DMAs landed.
        asm volatile("s_waitcnt vmcnt(1)" ::: "memory");
        __builtin_amdgcn_sched_barrier(0);
        do_batch(i);
    }

    // ---- combine the block's 4 waves in LDS
    #pragma unroll
    for (int k = 0; k < 2; ++k) {
        #pragma unroll
        for (int j = 0; j < 4; ++j)
            sc[wave][k * 256 + 4 * lane + j] = c[k * 4 + j];
    }
    __syncthreads();

    const int pidx = b * S_CHUNKS + chunk;
    for (int d = tid; d < DD; d += 256) {
        pc[(size_t)pidx * DD + d] = (sc[0][d] + sc[1][d]) + (sc[2][d] + sc[3][d]);
    }
}

// Fused epilogue, 4 blocks per batch b (R9/R10-proven)
__global__ __launch_bounds__(256) void attn_epilogue(
    const float* __restrict__ pexp, const float* __restrict__ pc,
    float* __restrict__ ctx_out, float* __restrict__ wout)
{
    const int b    = blockIdx.x >> 2;
    const int part = blockIdx.x & 3;
    const int tid  = threadIdx.x;
    const int wave = tid >> 6;

    float s = 0.f;
    #pragma unroll
    for (int k = 0; k < TT / 256; ++k) s += pexp[(size_t)b * TT + k * 256 + tid];
    #pragma unroll
    for (int off = 1; off < 64; off <<= 1) s += __shfl_xor(s, off, 64);

    __shared__ float sl[4];
    if ((tid & 63) == 0) sl[wave] = s;
    __syncthreads();
    const float l = (sl[0] + sl[1]) + (sl[2] + sl[3]);
    const float inv = 1.0f / l;

    const int d = part * (DD / 4) + tid;
    if (tid < DD / 4) {
        float v = 0.f;
        #pragma unroll
        for (int sss = 0; sss < S_CHUNKS; ++sss)
            v += pc[((size_t)(b * S_CHUNKS + sss)) * DD + d];
        ctx_out[(size_t)b * DD + d] = v * inv;
    }
    #pragma unroll
    for (int k = 0; k < 2; ++k) {
        const int t = part * (TT / 4) + k * 256 + tid;
        wout[(size_t)b * TT + t] = pexp[(size_t)b * TT + t] * inv;
    }
}

extern "C" void kernel_launch(void* const* d_in, const int* in_sizes, int n_in,
                              void* d_out, int out_size, void* d_ws, size_t ws_size,
                              hipStream_t stream) {
    const float* Eo   = (const float*)d_in[0];
    const float* H    = (const float*)d_in[1];
    const float* W_eo = (const float*)d_in[2];
    const float* b_eo = (const float*)d_in[3];
    const float* W_h  = (const float*)d_in[4];
    const float* b_h  = (const float*)d_in[5];
    const float* W_s  = (const float*)d_in[6];
    const float* b_s  = (const float*)d_in[7];

    // ws layout (floats): pexp[B*T] | pc[B*S*D]
    float* pexp = (float*)d_ws;
    float* pc   = pexp + (size_t)BB * TT;

    float* out_ctx = (float*)d_out;                 // [B, D]
    float* out_w   = out_ctx + (size_t)BB * DD;     // [B, T, 1]

    dim3 gridA(S_CHUNKS, BB);
    attn_pass1<<<gridA, 256, 0, stream>>>(Eo, H, W_eo, b_eo, W_h, b_h, W_s, b_s,
                                          pexp, pc);
    attn_epilogue<<<BB * 4, 256, 0, stream>>>(pexp, pc, out_ctx, out_w);
}